// Round 9
// baseline (314.581 us; speedup 1.0000x reference)
//
#include <hip/hip_runtime.h>
#include <hip/hip_fp16.h>
#include <math.h>

#define DIM 128
#define BINSH 10       // 1024 nodes per dst-bin
#define EPB 8192       // edges per bin_k block (196 blocks x 1024 thr)
#define PAD 18432      // padded bin capacity: mean 16384 + 16 sigma
// Build discipline (R6): per-EDGE global atomics ping-pong cache lines across
// the 8 non-coherent XCD L2s — catastrophic. All per-edge counting in LDS.
// R15: scatter RESERVATION RUNS must stay multi-line — concurrency via waves
// per block, not block count. R16 (verified): 1024-thr build blocks,
// padded-bin tmp. R18 (verified): T' = dis*(h@W) fold, weightless 4B ew,
// build fusion, 9-node graph. R19 (verified, 411->310): parallel pool
// geometry — fusion must preserve the parallelism of what it fuses.
// R20 FAILED: hipLaunchCooperativeKernel silently no-ops under the harness's
// graph capture (output stayed memset-zero). Grid-sync fusion is off the
// table; launch-API deviations must fail loudly.
// Agg concurrency ladder (R8-R13, verified): rate ~ outstanding gather BYTES
// per wave. 4B/lane->8B/lane (R13) = 57->40us at same 8-deep pipeline.
// R21: next rung — uint4 16B/lane, 8 lanes/row, 8 nodes/wave: one gather
// instr = 8 rows = 16 lines; 8-deep = 128 lines in flight/wave (2x R13).
// VALU/edge unchanged (~4us of 37 — not limiting). ~70 VGPR.

typedef __attribute__((ext_vector_type(8))) _Float16 half8;
typedef __attribute__((ext_vector_type(4))) float f32x4;
typedef __attribute__((ext_vector_type(2))) float f32x2;

// ---------------------------------------------------------------------------
// prep: zero bincur + weight pre-pack (conv_w fp32 -> fp16 MFMA fragments)
// ---------------------------------------------------------------------------
__global__ __launch_bounds__(256) void prep_k(const float* __restrict__ conv_w,
                                              _Float16* __restrict__ bp,
                                              int* __restrict__ bincur, int nbc) {
    int g = blockIdx.x * 256 + threadIdx.x;   // 24*256 = 6144 >= max(nbc, 3*2048)
    if (g < nbc) bincur[g] = 0;
    if (g >= 3 * 2048) return;
    int l = g >> 11;
    int rem = g & 2047;
    int c = rem >> 8;
    int f = (rem >> 6) & 3;
    int lane = rem & 63;
    const float* W = conv_w + l * DIM * DIM;
    int kbase = f * 32 + (lane >> 4) * 8;
    int col = c * 16 + (lane & 15);
    _Float16* d = bp + ((size_t)l * 2048 + (size_t)(c * 4 + f) * 64 + lane) * 8;
#pragma unroll
    for (int j = 0; j < 8; ++j)
        d[j] = (_Float16)W[(kbase + j) * DIM + col];
}

// ---------------------------------------------------------------------------
// Graph build: bin -> fused(hist+scan+rowse+dis+scatter)
// ---------------------------------------------------------------------------
__global__ __launch_bounds__(1024) void bin_k(const int* __restrict__ src,
                                              const int* __restrict__ dst,
                                              int* __restrict__ bincur,
                                              unsigned int* __restrict__ tmp,
                                              int E, int NBIN) {
    __shared__ int cur[128];
    const int t = threadIdx.x;
    if (t < 128) cur[t] = 0;
    __syncthreads();
    const int e0 = blockIdx.x * EPB;
    const int e1 = min(e0 + EPB, E);
    for (int e = e0 + t; e < e1; e += 1024)
        atomicAdd(&cur[dst[e] >> BINSH], 1);
    __syncthreads();
    if (t < NBIN) {
        int h = cur[t];
        cur[t] = h ? atomicAdd(&bincur[t * 16], h) : 0;
    }
    __syncthreads();
    for (int e = e0 + t; e < e1; e += 1024) {
        int d = dst[e], s = src[e];
        int b = d >> BINSH;
        int pos = atomicAdd(&cur[b], 1);
        if (pos < PAD)
            tmp[(size_t)b * PAD + pos] =
                (unsigned int)((s << BINSH) | (d & ((1 << BINSH) - 1)));
    }
}

// One block per bin. Stage bin in LDS, histogram, scan, emit rowse/dis,
// scatter cols to padded ew (start = b*PAD + excl). No cross-bin dependency.
__global__ __launch_bounds__(1024) void fused_k(const unsigned int* __restrict__ tmp,
                                                const int* __restrict__ bincur,
                                                int2* __restrict__ rowse,
                                                float* __restrict__ dis,
                                                int* __restrict__ ew, int n) {
    __shared__ unsigned int led[PAD];
    __shared__ int cnt[1 << BINSH];
    __shared__ int lcur[1 << BINSH];
    const int b = blockIdx.x, t = threadIdx.x;
    const int size = min(bincur[b * 16], PAD);
    const unsigned int* bt = tmp + (size_t)b * PAD;
    cnt[t] = 0;
    for (int e = t; e < size; e += 1024) led[e] = bt[e];
    __syncthreads();
    for (int e = t; e < size; e += 1024)
        atomicAdd(&cnt[led[e] & ((1 << BINSH) - 1)], 1);
    __syncthreads();
    int v = cnt[t];
    __syncthreads();
    for (int off = 1; off < 1024; off <<= 1) {      // inclusive ripple scan
        int u = (t >= off) ? cnt[t - off] : 0;
        __syncthreads();
        cnt[t] += u;
        __syncthreads();
    }
    int start = b * PAD + cnt[t] - v;
    lcur[t] = start;
    int node = (b << BINSH) + t;
    if (node < n) {
        rowse[node] = make_int2(start, start + v);
        dis[node] = rsqrtf((float)(v + 1));
    }
    __syncthreads();
    for (int e = t; e < size; e += 1024) {
        unsigned int u = led[e];
        int q = atomicAdd(&lcur[u & ((1 << BINSH) - 1)], 1);
        ew[q] = (int)(u >> BINSH);
    }
}

// ---------------------------------------------------------------------------
// MFMA GEMM (R17 direct-load + R18 dis-fold): T'[n,128](fp8) = dis * (A @ W).
// Each wave owns 16 rows; A-fragments loaded directly global->reg. D^T via
// operand swap -> lane owns 4 consecutive cols of ONE row -> uniform dis[row]
// scale -> packed 4B fp8 store.
// ---------------------------------------------------------------------------
template <bool FP16IN>
__global__ __launch_bounds__(256) void gemm_k(const void* __restrict__ Ain,
                                              const _Float16* __restrict__ Bp,
                                              const float* __restrict__ dis,
                                              unsigned int* __restrict__ T32, int n) {
    const int t = threadIdx.x;
    const int lane = t & 63;
    const int wave = t >> 6;
    const int quad = lane >> 4;
    const int m    = lane & 15;
    const int row  = blockIdx.x * 64 + wave * 16 + m;
    const bool act = row < n;

    half8 a[4];
    float dvr = 0.f;
    if (act) {
        dvr = dis[row];
        if (FP16IN) {
            const _Float16* A = (const _Float16*)Ain + (size_t)row * DIM;
#pragma unroll
            for (int f = 0; f < 4; ++f)
                a[f] = *(const half8*)(A + f * 32 + quad * 8);
        } else {
            const float* A = (const float*)Ain + (size_t)row * DIM;
#pragma unroll
            for (int f = 0; f < 4; ++f) {
                float4 v0 = *(const float4*)(A + f * 32 + quad * 8);
                float4 v1 = *(const float4*)(A + f * 32 + quad * 8 + 4);
                __half2 h01 = __floats2half2_rn(v0.x, v0.y);
                __half2 h23 = __floats2half2_rn(v0.z, v0.w);
                __half2 h45 = __floats2half2_rn(v1.x, v1.y);
                __half2 h67 = __floats2half2_rn(v1.z, v1.w);
                int4 pk;
                pk.x = *(int*)&h01; pk.y = *(int*)&h23;
                pk.z = *(int*)&h45; pk.w = *(int*)&h67;
                a[f] = *(half8*)&pk;
            }
        }
    } else {
#pragma unroll
        for (int f = 0; f < 4; ++f) a[f] = half8{};
    }

    const half8* B8 = (const half8*)Bp;   // 32KB/layer, hot in L1/L2
#pragma unroll
    for (int c = 0; c < 8; ++c) {
        f32x4 acc = {0.f, 0.f, 0.f, 0.f};
#pragma unroll
        for (int f = 0; f < 4; ++f) {
            half8 b = B8[(c * 4 + f) * 64 + lane];
            acc = __builtin_amdgcn_mfma_f32_16x16x32_f16(b, a[f], acc, 0, 0, 0);
        }
        if (act) {
            int r = 0;
            r = __builtin_amdgcn_cvt_pk_fp8_f32(dvr * acc[0], dvr * acc[1], r, 0);
            r = __builtin_amdgcn_cvt_pk_fp8_f32(dvr * acc[2], dvr * acc[3], r, 1);
            T32[(size_t)row * 32 + c * 4 + quad] = (unsigned int)r;
        }
    }
}

// ---------------------------------------------------------------------------
// Aggregation v3 (R21): O[v] = relu( dis[v] * (T'[v] + sum_e T'[col_e]) + b )
// 8 nodes/wave: lane = (oct o, li); oct owns node v = base+o; lane li (0..7)
// covers dims 16li..16li+15 via ONE uint4 (16B) load. One wave-gather instr
// = 8 edge-rows = 1KB = 16 cache lines; 8-deep unroll = 128 lines in
// flight/wave (2x R13). acc[16]/thread; two int4 stores.
// ---------------------------------------------------------------------------
#define ACC_E16(rr) { \
    f32x2 a0 = __builtin_amdgcn_cvt_pk_f32_fp8((int)rr.x, 0); \
    f32x2 a1 = __builtin_amdgcn_cvt_pk_f32_fp8((int)rr.x, 1); \
    f32x2 a2 = __builtin_amdgcn_cvt_pk_f32_fp8((int)rr.y, 0); \
    f32x2 a3 = __builtin_amdgcn_cvt_pk_f32_fp8((int)rr.y, 1); \
    f32x2 a4 = __builtin_amdgcn_cvt_pk_f32_fp8((int)rr.z, 0); \
    f32x2 a5 = __builtin_amdgcn_cvt_pk_f32_fp8((int)rr.z, 1); \
    f32x2 a6 = __builtin_amdgcn_cvt_pk_f32_fp8((int)rr.w, 0); \
    f32x2 a7 = __builtin_amdgcn_cvt_pk_f32_fp8((int)rr.w, 1); \
    acc[0]  += a0[0]; acc[1]  += a0[1]; acc[2]  += a1[0]; acc[3]  += a1[1]; \
    acc[4]  += a2[0]; acc[5]  += a2[1]; acc[6]  += a3[0]; acc[7]  += a3[1]; \
    acc[8]  += a4[0]; acc[9]  += a4[1]; acc[10] += a5[0]; acc[11] += a5[1]; \
    acc[12] += a6[0]; acc[13] += a6[1]; acc[14] += a7[0]; acc[15] += a7[1]; }

__global__ __launch_bounds__(256) void agg_k(const unsigned int* __restrict__ T32,
                                             const int2* __restrict__ rowse,
                                             const int* __restrict__ ew,
                                             const float* __restrict__ dis,
                                             const float* __restrict__ bias,
                                             __half* __restrict__ O, int n) {
    const int lane = threadIdx.x & 63;
    const int li   = lane & 7;         // uint4 (16 dims) within the row
    const int v = blockIdx.x * 32 + (threadIdx.x >> 6) * 8 + (lane >> 3);
    const bool act = v < n;

    const uint4* T4 = (const uint4*)T32;

    int e0 = 0, e1 = 0;
    float dv = 0.f;
    if (act) {
        int2 re = rowse[v];
        e0 = re.x; e1 = re.y;
        dv = dis[v];
    }

    float acc[16] = {0.f, 0.f, 0.f, 0.f, 0.f, 0.f, 0.f, 0.f,
                     0.f, 0.f, 0.f, 0.f, 0.f, 0.f, 0.f, 0.f};

    // self term (weightless under the T' formulation)
    if (act) {
        uint4 rs = T4[(size_t)v * 8 + li];
        ACC_E16(rs);
    }

    int e = e0;
    for (; e + 8 <= e1; e += 8) {
        int c0 = ew[e + 0], c1 = ew[e + 1], c2 = ew[e + 2], c3 = ew[e + 3];
        int c4 = ew[e + 4], c5 = ew[e + 5], c6 = ew[e + 6], c7 = ew[e + 7];
        uint4 r0 = T4[(size_t)c0 * 8 + li];
        uint4 r1 = T4[(size_t)c1 * 8 + li];
        uint4 r2 = T4[(size_t)c2 * 8 + li];
        uint4 r3 = T4[(size_t)c3 * 8 + li];
        uint4 r4 = T4[(size_t)c4 * 8 + li];
        uint4 r5 = T4[(size_t)c5 * 8 + li];
        uint4 r6 = T4[(size_t)c6 * 8 + li];
        uint4 r7 = T4[(size_t)c7 * 8 + li];
        ACC_E16(r0); ACC_E16(r1); ACC_E16(r2); ACC_E16(r3);
        ACC_E16(r4); ACC_E16(r5); ACC_E16(r6); ACC_E16(r7);
    }
    for (; e + 4 <= e1; e += 4) {
        int c0 = ew[e + 0], c1 = ew[e + 1], c2 = ew[e + 2], c3 = ew[e + 3];
        uint4 r0 = T4[(size_t)c0 * 8 + li];
        uint4 r1 = T4[(size_t)c1 * 8 + li];
        uint4 r2 = T4[(size_t)c2 * 8 + li];
        uint4 r3 = T4[(size_t)c3 * 8 + li];
        ACC_E16(r0); ACC_E16(r1); ACC_E16(r2); ACC_E16(r3);
    }
    for (; e + 2 <= e1; e += 2) {
        int c0 = ew[e + 0], c1 = ew[e + 1];
        uint4 r0 = T4[(size_t)c0 * 8 + li];
        uint4 r1 = T4[(size_t)c1 * 8 + li];
        ACC_E16(r0); ACC_E16(r1);
    }
    if (e < e1) {
        uint4 r0 = T4[(size_t)ew[e] * 8 + li];
        ACC_E16(r0);
    }

    if (act) {
        float4 b0 = ((const float4*)bias)[li * 4 + 0];
        float4 b1 = ((const float4*)bias)[li * 4 + 1];
        float4 b2 = ((const float4*)bias)[li * 4 + 2];
        float4 b3 = ((const float4*)bias)[li * 4 + 3];
        __half2 o0 = __floats2half2_rn(fmaxf(dv * acc[0]  + b0.x, 0.f),
                                       fmaxf(dv * acc[1]  + b0.y, 0.f));
        __half2 o1 = __floats2half2_rn(fmaxf(dv * acc[2]  + b0.z, 0.f),
                                       fmaxf(dv * acc[3]  + b0.w, 0.f));
        __half2 o2 = __floats2half2_rn(fmaxf(dv * acc[4]  + b1.x, 0.f),
                                       fmaxf(dv * acc[5]  + b1.y, 0.f));
        __half2 o3 = __floats2half2_rn(fmaxf(dv * acc[6]  + b1.z, 0.f),
                                       fmaxf(dv * acc[7]  + b1.w, 0.f));
        __half2 o4 = __floats2half2_rn(fmaxf(dv * acc[8]  + b2.x, 0.f),
                                       fmaxf(dv * acc[9]  + b2.y, 0.f));
        __half2 o5 = __floats2half2_rn(fmaxf(dv * acc[10] + b2.z, 0.f),
                                       fmaxf(dv * acc[11] + b2.w, 0.f));
        __half2 o6 = __floats2half2_rn(fmaxf(dv * acc[12] + b3.x, 0.f),
                                       fmaxf(dv * acc[13] + b3.y, 0.f));
        __half2 o7 = __floats2half2_rn(fmaxf(dv * acc[14] + b3.z, 0.f),
                                       fmaxf(dv * acc[15] + b3.w, 0.f));
        int4 s0, s1;
        s0.x = *(int*)&o0; s0.y = *(int*)&o1; s0.z = *(int*)&o2; s0.w = *(int*)&o3;
        s1.x = *(int*)&o4; s1.y = *(int*)&o5; s1.z = *(int*)&o6; s1.w = *(int*)&o7;
        int4* dst = (int4*)(O + (size_t)v * DIM + li * 16);
        dst[0] = s0;
        dst[1] = s1;
    }
}

// ---------------------------------------------------------------------------
// Fused pool+head (R19 parallel geometry): 1024 threads = 64 row-groups x 16
// lanes. Lane li loads int4 (8 fp16 dims) of its rows (stride 64) -> ~12
// independent 16B loads per thread per graph. LDS tree-reduce over groups,
// then head (lin1/relu/lin2/log_softmax) on threads 0-127.
// ---------------------------------------------------------------------------
__global__ __launch_bounds__(1024) void poolhead_k(const __half* __restrict__ H,
                                                   const int* __restrict__ batch,
                                                   const float* __restrict__ l1w,
                                                   const float* __restrict__ l1b,
                                                   const float* __restrict__ l2w,
                                                   const float* __restrict__ l2b,
                                                   float* __restrict__ out, int n) {
    const int g = blockIdx.x, t = threadIdx.x;
    const int g8 = t >> 4;          // row-group 0..63
    const int li = t & 15;          // int4 (8 dims) within row
    __shared__ float red[1024 * 8];  // 32 KB partials
    __shared__ float gs[128];

    int lo = 0, hi = n;
    while (lo < hi) { int m = (lo + hi) >> 1; if (batch[m] < g) lo = m + 1; else hi = m; }
    int start = lo;
    lo = start; hi = n;
    while (lo < hi) { int m = (lo + hi) >> 1; if (batch[m] < g + 1) lo = m + 1; else hi = m; }
    int end = lo;
    int cnt = end - start;

    float s[8] = {0.f, 0.f, 0.f, 0.f, 0.f, 0.f, 0.f, 0.f};
    for (int v = start + g8; v < end; v += 64) {
        int4 pk = *((const int4*)(H + (size_t)v * DIM) + li);
        const __half2* h2 = (const __half2*)&pk;
#pragma unroll
        for (int j = 0; j < 4; ++j) {
            float2 f = __half22float2(h2[j]);
            s[2 * j + 0] += f.x;
            s[2 * j + 1] += f.y;
        }
    }
#pragma unroll
    for (int j = 0; j < 8; ++j) red[t * 8 + j] = s[j];
    __syncthreads();
    for (int st = 32; st > 0; st >>= 1) {
        if (g8 < st) {
#pragma unroll
            for (int j = 0; j < 8; ++j)
                red[t * 8 + j] += red[(t + st * 16) * 8 + j];
        }
        __syncthreads();
    }
    if (t < 16) {
        float inv = cnt > 0 ? 1.f / (float)cnt : 0.f;
#pragma unroll
        for (int j = 0; j < 8; ++j) gs[t * 8 + j] = red[t * 8 + j] * inv;
    }
    __syncthreads();

    // head on threads 0..127
    float y = 0.f;
    if (t < 128) {
        float acc = l1b[t];
        for (int k = 0; k < 128; ++k) acc += gs[k] * l1w[k * 128 + t];
        y = fmaxf(acc, 0.f);
    }
    float2* red2 = (float2*)red;
    if (t < 128) red2[t] = make_float2(y * l2w[t * 2 + 0], y * l2w[t * 2 + 1]);
    __syncthreads();
    for (int sfd = 64; sfd > 0; sfd >>= 1) {
        if (t < sfd) {
            red2[t].x += red2[t + sfd].x;
            red2[t].y += red2[t + sfd].y;
        }
        __syncthreads();
    }
    if (t == 0) {
        float l0 = red2[0].x + l2b[0];
        float l1 = red2[0].y + l2b[1];
        float m = fmaxf(l0, l1);
        float lse = m + logf(expf(l0 - m) + expf(l1 - m));
        out[g * 2 + 0] = l0 - lse;
        out[g * 2 + 1] = l1 - lse;
    }
}

// ---------------------------------------------------------------------------
// Launch — 9 graph nodes total
// ---------------------------------------------------------------------------
extern "C" void kernel_launch(void* const* d_in, const int* in_sizes, int n_in,
                              void* d_out, int out_size, void* d_ws, size_t ws_size,
                              hipStream_t stream) {
    const float* x       = (const float*)d_in[0];
    const int*   ei      = (const int*)d_in[1];
    const int*   batch   = (const int*)d_in[2];
    const float* conv_w  = (const float*)d_in[3];
    const float* conv_b  = (const float*)d_in[4];
    const float* lin1_w  = (const float*)d_in[5];
    const float* lin1_b  = (const float*)d_in[6];
    const float* lin2_w  = (const float*)d_in[7];
    const float* lin2_b  = (const float*)d_in[8];
    float* out = (float*)d_out;

    const int n = in_sizes[0] / DIM;      // 100000
    const int E = in_sizes[1] / 2;        // 1600000
    const int n_graphs = 128;
    const int NBIN = (n + (1 << BINSH) - 1) >> BINSH;   // 98 dst-bins

    const int* src = ei;
    const int* dst = ei + E;

    // workspace layout (all 256B aligned)
    char* p = (char*)d_ws;
    auto alloc = [&](size_t bytes) {
        char* r = p;
        p += (bytes + 255) & ~(size_t)255;
        return r;
    };
    __half*        bufH    = (__half*)alloc((size_t)n * DIM * 2);       // agg output (fp16)
    unsigned int*  bufT    = (unsigned int*)alloc((size_t)n * DIM);     // gemm output (fp8 T')
    float*         dis     = (float*)alloc((size_t)n * 4);
    int2*          rowse   = (int2*)alloc((size_t)n * 8);               // {start,end} into ew
    int*           bincur  = (int*)alloc((size_t)NBIN * 16 * 4);
    unsigned int*  tmp     = (unsigned int*)alloc((size_t)NBIN * PAD * 4); // packed {src,dstlo}
    int*           ew      = (int*)alloc((size_t)NBIN * PAD * 4);       // padded CSR cols
    _Float16*      bp      = (_Float16*)alloc((size_t)3 * 2048 * 8 * 2);
    (void)ws_size;

    const int binBlocks = (E + EPB - 1) / EPB;      // 196

    prep_k<<<24, 256, 0, stream>>>(conv_w, bp, bincur, NBIN * 16);
    bin_k<<<binBlocks, 1024, 0, stream>>>(src, dst, bincur, tmp, E, NBIN);
    fused_k<<<NBIN, 1024, 0, stream>>>(tmp, bincur, rowse, dis, ew, n);

    const int gemmBlocks = (n + 63) / 64;
    const int aggBlocks = (n + 31) / 32;

    // layer 0: x (fp32) -> bufT(fp8 T') -> bufH(fp16)
    gemm_k<false><<<gemmBlocks, 256, 0, stream>>>((const void*)x, bp + 0 * 16384, dis, bufT, n);
    agg_k<<<aggBlocks, 256, 0, stream>>>(bufT, rowse, ew, dis, conv_b + 0 * DIM, bufH, n);
    // layer 1
    gemm_k<true><<<gemmBlocks, 256, 0, stream>>>((const void*)bufH, bp + 1 * 16384, dis, bufT, n);
    agg_k<<<aggBlocks, 256, 0, stream>>>(bufT, rowse, ew, dis, conv_b + 1 * DIM, bufH, n);
    // layer 2
    gemm_k<true><<<gemmBlocks, 256, 0, stream>>>((const void*)bufH, bp + 2 * 16384, dis, bufT, n);
    agg_k<<<aggBlocks, 256, 0, stream>>>(bufT, rowse, ew, dis, conv_b + 2 * DIM, bufH, n);

    poolhead_k<<<n_graphs, 1024, 0, stream>>>(bufH, batch, lin1_w, lin1_b, lin2_w, lin2_b, out, n);
}

// Round 10
// 312.175 us; speedup vs baseline: 1.0077x; 1.0077x over previous
//
#include <hip/hip_runtime.h>
#include <hip/hip_fp16.h>
#include <math.h>

#define DIM 128
#define BINSH 10       // 1024 nodes per dst-bin
#define EPB 8192       // edges per bin_k block (196 blocks x 1024 thr)
#define PAD 18432      // padded bin capacity: mean 16384 + 16 sigma
#define ALH 136        // LDS row stride in halves (agg->gemm handoff)
// Build discipline (R6): per-EDGE global atomics ping-pong cache lines across
// the 8 non-coherent XCD L2s — catastrophic. All per-edge counting in LDS.
// R15: scatter RESERVATION RUNS must stay multi-line — concurrency via waves
// per block, not block count. R16 (verified): 1024-thr build blocks,
// padded-bin tmp. R18 (verified): T' = dis*(h@W) fold, weightless 4B ew.
// R19 (verified, 411->310): parallel pool geometry. R20 FAILED:
// hipLaunchCooperativeKernel silently no-ops under graph capture.
// R21 (neutral, 314.6): uint4 16B/lane gather rung bought nothing ->
// bytes-per-request ladder EXHAUSTED; agg at ~6.4 TB/s effective = memory
// system ceiling. Reverted to R19 uint2 geometry.
// R22: block-local fusion agg_l -> gemm_{l+1}. gemm{l+1} reads ONLY the
// rows its block computes (row-local; unlike gemm->agg's random gather),
// so the handoff lives in LDS with one __syncthreads — no grid sync.
// Layers 0/1 bufH never touches HBM (-100MB). 10 nodes -> 8.

typedef __attribute__((ext_vector_type(8))) _Float16 half8;
typedef __attribute__((ext_vector_type(4))) float f32x4;
typedef __attribute__((ext_vector_type(2))) float f32x2;

// ---------------------------------------------------------------------------
// prep: zero bincur + weight pre-pack (conv_w fp32 -> fp16 MFMA fragments)
// ---------------------------------------------------------------------------
__global__ __launch_bounds__(256) void prep_k(const float* __restrict__ conv_w,
                                              _Float16* __restrict__ bp,
                                              int* __restrict__ bincur, int nbc) {
    int g = blockIdx.x * 256 + threadIdx.x;   // 24*256 = 6144 >= max(nbc, 3*2048)
    if (g < nbc) bincur[g] = 0;
    if (g >= 3 * 2048) return;
    int l = g >> 11;
    int rem = g & 2047;
    int c = rem >> 8;
    int f = (rem >> 6) & 3;
    int lane = rem & 63;
    const float* W = conv_w + l * DIM * DIM;
    int kbase = f * 32 + (lane >> 4) * 8;
    int col = c * 16 + (lane & 15);
    _Float16* d = bp + ((size_t)l * 2048 + (size_t)(c * 4 + f) * 64 + lane) * 8;
#pragma unroll
    for (int j = 0; j < 8; ++j)
        d[j] = (_Float16)W[(kbase + j) * DIM + col];
}

// ---------------------------------------------------------------------------
// Graph build: bin -> fused(hist+scan+rowse+dis+scatter)
// ---------------------------------------------------------------------------
__global__ __launch_bounds__(1024) void bin_k(const int* __restrict__ src,
                                              const int* __restrict__ dst,
                                              int* __restrict__ bincur,
                                              unsigned int* __restrict__ tmp,
                                              int E, int NBIN) {
    __shared__ int cur[128];
    const int t = threadIdx.x;
    if (t < 128) cur[t] = 0;
    __syncthreads();
    const int e0 = blockIdx.x * EPB;
    const int e1 = min(e0 + EPB, E);
    for (int e = e0 + t; e < e1; e += 1024)
        atomicAdd(&cur[dst[e] >> BINSH], 1);
    __syncthreads();
    if (t < NBIN) {
        int h = cur[t];
        cur[t] = h ? atomicAdd(&bincur[t * 16], h) : 0;
    }
    __syncthreads();
    for (int e = e0 + t; e < e1; e += 1024) {
        int d = dst[e], s = src[e];
        int b = d >> BINSH;
        int pos = atomicAdd(&cur[b], 1);
        if (pos < PAD)
            tmp[(size_t)b * PAD + pos] =
                (unsigned int)((s << BINSH) | (d & ((1 << BINSH) - 1)));
    }
}

// One block per bin. Stage bin in LDS, histogram, scan, emit rowse/dis,
// scatter cols to padded ew (start = b*PAD + excl). No cross-bin dependency.
__global__ __launch_bounds__(1024) void fused_k(const unsigned int* __restrict__ tmp,
                                                const int* __restrict__ bincur,
                                                int2* __restrict__ rowse,
                                                float* __restrict__ dis,
                                                int* __restrict__ ew, int n) {
    __shared__ unsigned int led[PAD];
    __shared__ int cnt[1 << BINSH];
    __shared__ int lcur[1 << BINSH];
    const int b = blockIdx.x, t = threadIdx.x;
    const int size = min(bincur[b * 16], PAD);
    const unsigned int* bt = tmp + (size_t)b * PAD;
    cnt[t] = 0;
    for (int e = t; e < size; e += 1024) led[e] = bt[e];
    __syncthreads();
    for (int e = t; e < size; e += 1024)
        atomicAdd(&cnt[led[e] & ((1 << BINSH) - 1)], 1);
    __syncthreads();
    int v = cnt[t];
    __syncthreads();
    for (int off = 1; off < 1024; off <<= 1) {      // inclusive ripple scan
        int u = (t >= off) ? cnt[t - off] : 0;
        __syncthreads();
        cnt[t] += u;
        __syncthreads();
    }
    int start = b * PAD + cnt[t] - v;
    lcur[t] = start;
    int node = (b << BINSH) + t;
    if (node < n) {
        rowse[node] = make_int2(start, start + v);
        dis[node] = rsqrtf((float)(v + 1));
    }
    __syncthreads();
    for (int e = t; e < size; e += 1024) {
        unsigned int u = led[e];
        int q = atomicAdd(&lcur[u & ((1 << BINSH) - 1)], 1);
        ew[q] = (int)(u >> BINSH);
    }
}

// ---------------------------------------------------------------------------
// Shared agg inner loop (R19 uint2 geometry): accumulate sum of T' rows
// listed in ew[e0..e1) at word-pair li into acc[8]. Weightless (T' fold).
// ---------------------------------------------------------------------------
#define ACC_EDGE(rr) { \
    f32x2 a0 = __builtin_amdgcn_cvt_pk_f32_fp8((int)rr.x, 0); \
    f32x2 a1 = __builtin_amdgcn_cvt_pk_f32_fp8((int)rr.x, 1); \
    f32x2 a2 = __builtin_amdgcn_cvt_pk_f32_fp8((int)rr.y, 0); \
    f32x2 a3 = __builtin_amdgcn_cvt_pk_f32_fp8((int)rr.y, 1); \
    acc[0] += a0[0]; acc[1] += a0[1]; \
    acc[2] += a1[0]; acc[3] += a1[1]; \
    acc[4] += a2[0]; acc[5] += a2[1]; \
    acc[6] += a3[0]; acc[7] += a3[1]; }

__device__ __forceinline__ void agg_edges(const uint2* __restrict__ T2,
                                          const int* __restrict__ ew,
                                          int e0, int e1, int li, float* acc) {
    int e = e0;
    for (; e + 8 <= e1; e += 8) {
        int c0 = ew[e + 0], c1 = ew[e + 1], c2 = ew[e + 2], c3 = ew[e + 3];
        int c4 = ew[e + 4], c5 = ew[e + 5], c6 = ew[e + 6], c7 = ew[e + 7];
        uint2 r0 = T2[(size_t)c0 * 16 + li];
        uint2 r1 = T2[(size_t)c1 * 16 + li];
        uint2 r2 = T2[(size_t)c2 * 16 + li];
        uint2 r3 = T2[(size_t)c3 * 16 + li];
        uint2 r4 = T2[(size_t)c4 * 16 + li];
        uint2 r5 = T2[(size_t)c5 * 16 + li];
        uint2 r6 = T2[(size_t)c6 * 16 + li];
        uint2 r7 = T2[(size_t)c7 * 16 + li];
        ACC_EDGE(r0); ACC_EDGE(r1); ACC_EDGE(r2); ACC_EDGE(r3);
        ACC_EDGE(r4); ACC_EDGE(r5); ACC_EDGE(r6); ACC_EDGE(r7);
    }
    for (; e + 4 <= e1; e += 4) {
        int c0 = ew[e + 0], c1 = ew[e + 1], c2 = ew[e + 2], c3 = ew[e + 3];
        uint2 r0 = T2[(size_t)c0 * 16 + li];
        uint2 r1 = T2[(size_t)c1 * 16 + li];
        uint2 r2 = T2[(size_t)c2 * 16 + li];
        uint2 r3 = T2[(size_t)c3 * 16 + li];
        ACC_EDGE(r0); ACC_EDGE(r1); ACC_EDGE(r2); ACC_EDGE(r3);
    }
    for (; e + 2 <= e1; e += 2) {
        int c0 = ew[e + 0], c1 = ew[e + 1];
        uint2 r0 = T2[(size_t)c0 * 16 + li];
        uint2 r1 = T2[(size_t)c1 * 16 + li];
        ACC_EDGE(r0); ACC_EDGE(r1);
    }
    if (e < e1) {
        uint2 r0 = T2[(size_t)ew[e] * 16 + li];
        ACC_EDGE(r0);
    }
}

// ---------------------------------------------------------------------------
// MFMA GEMM (layer 0 only): T'[n,128](fp8) = dis * (x @ W0), fp32 input,
// direct global->reg A-fragments (R17).
// ---------------------------------------------------------------------------
__global__ __launch_bounds__(256) void gemm_k(const float* __restrict__ Ain,
                                              const _Float16* __restrict__ Bp,
                                              const float* __restrict__ dis,
                                              unsigned int* __restrict__ T32, int n) {
    const int t = threadIdx.x;
    const int lane = t & 63;
    const int wave = t >> 6;
    const int quad = lane >> 4;
    const int m    = lane & 15;
    const int row  = blockIdx.x * 64 + wave * 16 + m;
    const bool act = row < n;

    half8 a[4];
    float dvr = 0.f;
    if (act) {
        dvr = dis[row];
        const float* A = Ain + (size_t)row * DIM;
#pragma unroll
        for (int f = 0; f < 4; ++f) {
            float4 v0 = *(const float4*)(A + f * 32 + quad * 8);
            float4 v1 = *(const float4*)(A + f * 32 + quad * 8 + 4);
            __half2 h01 = __floats2half2_rn(v0.x, v0.y);
            __half2 h23 = __floats2half2_rn(v0.z, v0.w);
            __half2 h45 = __floats2half2_rn(v1.x, v1.y);
            __half2 h67 = __floats2half2_rn(v1.z, v1.w);
            int4 pk;
            pk.x = *(int*)&h01; pk.y = *(int*)&h23;
            pk.z = *(int*)&h45; pk.w = *(int*)&h67;
            a[f] = *(half8*)&pk;
        }
    } else {
#pragma unroll
        for (int f = 0; f < 4; ++f) a[f] = half8{};
    }

    const half8* B8 = (const half8*)Bp;   // 32KB/layer, hot in L1/L2
#pragma unroll
    for (int c = 0; c < 8; ++c) {
        f32x4 acc = {0.f, 0.f, 0.f, 0.f};
#pragma unroll
        for (int f = 0; f < 4; ++f) {
            half8 b = B8[(c * 4 + f) * 64 + lane];
            acc = __builtin_amdgcn_mfma_f32_16x16x32_f16(b, a[f], acc, 0, 0, 0);
        }
        if (act) {
            int r = 0;
            r = __builtin_amdgcn_cvt_pk_fp8_f32(dvr * acc[0], dvr * acc[1], r, 0);
            r = __builtin_amdgcn_cvt_pk_fp8_f32(dvr * acc[2], dvr * acc[3], r, 1);
            T32[(size_t)row * 32 + c * 4 + quad] = (unsigned int)r;
        }
    }
}

// ---------------------------------------------------------------------------
// R22 fused agg_l + gemm_{l+1}: block owns 64 nodes.
// Phase A (agg, R19 geometry): 4 waves x 4 sub-tiles x 4 nodes; lane li
// holds dims 8li..8li+7. O row = relu(dis*(self+sum)+b) -> LDS fp16
// (ALH-strided). One __syncthreads.
// Phase B (gemm, LDS-read): lane reads a[4] fragments of its row, MFMA with
// W_{l+1}, dis-scale, fp8 store to Tout. No HBM round-trip for O.
// ---------------------------------------------------------------------------
__global__ __launch_bounds__(256) void aggemm_k(const unsigned int* __restrict__ Tin,
                                                const int2* __restrict__ rowse,
                                                const int* __restrict__ ew,
                                                const float* __restrict__ dis,
                                                const float* __restrict__ bias,
                                                const _Float16* __restrict__ Bp,
                                                unsigned int* __restrict__ Tout,
                                                int n) {
    __shared__ _Float16 Al[64 * ALH];
    const int lane = threadIdx.x & 63;
    const int wv   = threadIdx.x >> 6;   // wave 0..3
    const int li   = lane & 15;          // word-pair (8 dims) within row
    const int qd   = lane >> 4;          // node within wave's quartet
    const int r0   = blockIdx.x * 64;
    const uint2* T2 = (const uint2*)Tin;

    float4 b0 = ((const float4*)bias)[li * 2 + 0];
    float4 b1 = ((const float4*)bias)[li * 2 + 1];

    // ---- Phase A: aggregate 64 rows into LDS ----
#pragma unroll
    for (int sub = 0; sub < 4; ++sub) {
        const int lrow = sub * 16 + wv * 4 + qd;
        const int v = r0 + lrow;
        const bool act = v < n;
        int e0 = 0, e1 = 0;
        float dv = 0.f;
        if (act) {
            int2 re = rowse[v];
            e0 = re.x; e1 = re.y;
            dv = dis[v];
        }
        float acc[8] = {0.f, 0.f, 0.f, 0.f, 0.f, 0.f, 0.f, 0.f};
        if (act) {
            uint2 rs = T2[(size_t)v * 16 + li];
            ACC_EDGE(rs);
        }
        agg_edges(T2, ew, e0, e1, li, acc);

        __half2 o0 = __floats2half2_rn(fmaxf(dv * acc[0] + b0.x, 0.f),
                                       fmaxf(dv * acc[1] + b0.y, 0.f));
        __half2 o1 = __floats2half2_rn(fmaxf(dv * acc[2] + b0.z, 0.f),
                                       fmaxf(dv * acc[3] + b0.w, 0.f));
        __half2 o2 = __floats2half2_rn(fmaxf(dv * acc[4] + b1.x, 0.f),
                                       fmaxf(dv * acc[5] + b1.y, 0.f));
        __half2 o3 = __floats2half2_rn(fmaxf(dv * acc[6] + b1.z, 0.f),
                                       fmaxf(dv * acc[7] + b1.w, 0.f));
        int4 o;
        if (act) {
            o.x = *(int*)&o0; o.y = *(int*)&o1; o.z = *(int*)&o2; o.w = *(int*)&o3;
        } else {
            o = make_int4(0, 0, 0, 0);
        }
        *(int4*)&Al[lrow * ALH + li * 8] = o;
    }
    __syncthreads();

    // ---- Phase B: gemm from LDS ----
    const int quad = lane >> 4;
    const int m    = lane & 15;
    const int lrow = wv * 16 + m;
    const int row  = r0 + lrow;
    const bool act = row < n;

    half8 a[4];
#pragma unroll
    for (int f = 0; f < 4; ++f)
        a[f] = *(const half8*)&Al[lrow * ALH + f * 32 + quad * 8];
    float dvr = act ? dis[row] : 0.f;

    const half8* B8 = (const half8*)Bp;
#pragma unroll
    for (int c = 0; c < 8; ++c) {
        f32x4 acc = {0.f, 0.f, 0.f, 0.f};
#pragma unroll
        for (int f = 0; f < 4; ++f) {
            half8 b = B8[(c * 4 + f) * 64 + lane];
            acc = __builtin_amdgcn_mfma_f32_16x16x32_f16(b, a[f], acc, 0, 0, 0);
        }
        if (act) {
            int r = 0;
            r = __builtin_amdgcn_cvt_pk_fp8_f32(dvr * acc[0], dvr * acc[1], r, 0);
            r = __builtin_amdgcn_cvt_pk_fp8_f32(dvr * acc[2], dvr * acc[3], r, 1);
            Tout[(size_t)row * 32 + c * 4 + quad] = (unsigned int)r;
        }
    }
}

// ---------------------------------------------------------------------------
// Final aggregation (layer 2, R19 uint2 geometry): O -> bufH fp16 for pool.
// ---------------------------------------------------------------------------
__global__ __launch_bounds__(256) void agg_k(const unsigned int* __restrict__ T32,
                                             const int2* __restrict__ rowse,
                                             const int* __restrict__ ew,
                                             const float* __restrict__ dis,
                                             const float* __restrict__ bias,
                                             __half* __restrict__ O, int n) {
    const int lane = threadIdx.x & 63;
    const int li   = lane & 15;
    const int v = blockIdx.x * 16 + (threadIdx.x >> 6) * 4 + (lane >> 4);
    const bool act = v < n;

    const uint2* T2 = (const uint2*)T32;

    int e0 = 0, e1 = 0;
    float dv = 0.f;
    if (act) {
        int2 re = rowse[v];
        e0 = re.x; e1 = re.y;
        dv = dis[v];
    }

    float acc[8] = {0.f, 0.f, 0.f, 0.f, 0.f, 0.f, 0.f, 0.f};
    if (act) {
        uint2 rs = T2[(size_t)v * 16 + li];
        ACC_EDGE(rs);
    }
    agg_edges(T2, ew, e0, e1, li, acc);

    if (act) {
        float4 b0 = ((const float4*)bias)[li * 2 + 0];
        float4 b1 = ((const float4*)bias)[li * 2 + 1];
        __half2 o0 = __floats2half2_rn(fmaxf(dv * acc[0] + b0.x, 0.f),
                                       fmaxf(dv * acc[1] + b0.y, 0.f));
        __half2 o1 = __floats2half2_rn(fmaxf(dv * acc[2] + b0.z, 0.f),
                                       fmaxf(dv * acc[3] + b0.w, 0.f));
        __half2 o2 = __floats2half2_rn(fmaxf(dv * acc[4] + b1.x, 0.f),
                                       fmaxf(dv * acc[5] + b1.y, 0.f));
        __half2 o3 = __floats2half2_rn(fmaxf(dv * acc[6] + b1.z, 0.f),
                                       fmaxf(dv * acc[7] + b1.w, 0.f));
        int4 o;
        o.x = *(int*)&o0; o.y = *(int*)&o1; o.z = *(int*)&o2; o.w = *(int*)&o3;
        *(int4*)(O + (size_t)v * DIM + li * 8) = o;
    }
}

// ---------------------------------------------------------------------------
// Fused pool+head (R19 parallel geometry): 1024 threads = 64 row-groups x 16
// lanes; LDS tree-reduce; head on threads 0-127.
// ---------------------------------------------------------------------------
__global__ __launch_bounds__(1024) void poolhead_k(const __half* __restrict__ H,
                                                   const int* __restrict__ batch,
                                                   const float* __restrict__ l1w,
                                                   const float* __restrict__ l1b,
                                                   const float* __restrict__ l2w,
                                                   const float* __restrict__ l2b,
                                                   float* __restrict__ out, int n) {
    const int g = blockIdx.x, t = threadIdx.x;
    const int g8 = t >> 4;          // row-group 0..63
    const int li = t & 15;          // int4 (8 dims) within row
    __shared__ float red[1024 * 8];  // 32 KB partials
    __shared__ float gs[128];

    int lo = 0, hi = n;
    while (lo < hi) { int m = (lo + hi) >> 1; if (batch[m] < g) lo = m + 1; else hi = m; }
    int start = lo;
    lo = start; hi = n;
    while (lo < hi) { int m = (lo + hi) >> 1; if (batch[m] < g + 1) lo = m + 1; else hi = m; }
    int end = lo;
    int cnt = end - start;

    float s[8] = {0.f, 0.f, 0.f, 0.f, 0.f, 0.f, 0.f, 0.f};
    for (int v = start + g8; v < end; v += 64) {
        int4 pk = *((const int4*)(H + (size_t)v * DIM) + li);
        const __half2* h2 = (const __half2*)&pk;
#pragma unroll
        for (int j = 0; j < 4; ++j) {
            float2 f = __half22float2(h2[j]);
            s[2 * j + 0] += f.x;
            s[2 * j + 1] += f.y;
        }
    }
#pragma unroll
    for (int j = 0; j < 8; ++j) red[t * 8 + j] = s[j];
    __syncthreads();
    for (int st = 32; st > 0; st >>= 1) {
        if (g8 < st) {
#pragma unroll
            for (int j = 0; j < 8; ++j)
                red[t * 8 + j] += red[(t + st * 16) * 8 + j];
        }
        __syncthreads();
    }
    if (t < 16) {
        float inv = cnt > 0 ? 1.f / (float)cnt : 0.f;
#pragma unroll
        for (int j = 0; j < 8; ++j) gs[t * 8 + j] = red[t * 8 + j] * inv;
    }
    __syncthreads();

    // head on threads 0..127
    float y = 0.f;
    if (t < 128) {
        float acc = l1b[t];
        for (int k = 0; k < 128; ++k) acc += gs[k] * l1w[k * 128 + t];
        y = fmaxf(acc, 0.f);
    }
    float2* red2 = (float2*)red;
    if (t < 128) red2[t] = make_float2(y * l2w[t * 2 + 0], y * l2w[t * 2 + 1]);
    __syncthreads();
    for (int sfd = 64; sfd > 0; sfd >>= 1) {
        if (t < sfd) {
            red2[t].x += red2[t + sfd].x;
            red2[t].y += red2[t + sfd].y;
        }
        __syncthreads();
    }
    if (t == 0) {
        float l0 = red2[0].x + l2b[0];
        float l1 = red2[0].y + l2b[1];
        float m = fmaxf(l0, l1);
        float lse = m + logf(expf(l0 - m) + expf(l1 - m));
        out[g * 2 + 0] = l0 - lse;
        out[g * 2 + 1] = l1 - lse;
    }
}

// ---------------------------------------------------------------------------
// Launch — 8 graph nodes: prep, bin, fused, gemm0, AG1, AG2, agg2, poolhead
// ---------------------------------------------------------------------------
extern "C" void kernel_launch(void* const* d_in, const int* in_sizes, int n_in,
                              void* d_out, int out_size, void* d_ws, size_t ws_size,
                              hipStream_t stream) {
    const float* x       = (const float*)d_in[0];
    const int*   ei      = (const int*)d_in[1];
    const int*   batch   = (const int*)d_in[2];
    const float* conv_w  = (const float*)d_in[3];
    const float* conv_b  = (const float*)d_in[4];
    const float* lin1_w  = (const float*)d_in[5];
    const float* lin1_b  = (const float*)d_in[6];
    const float* lin2_w  = (const float*)d_in[7];
    const float* lin2_b  = (const float*)d_in[8];
    float* out = (float*)d_out;

    const int n = in_sizes[0] / DIM;      // 100000
    const int E = in_sizes[1] / 2;        // 1600000
    const int n_graphs = 128;
    const int NBIN = (n + (1 << BINSH) - 1) >> BINSH;   // 98 dst-bins

    const int* src = ei;
    const int* dst = ei + E;

    // workspace layout (all 256B aligned)
    char* p = (char*)d_ws;
    auto alloc = [&](size_t bytes) {
        char* r = p;
        p += (bytes + 255) & ~(size_t)255;
        return r;
    };
    __half*        bufH    = (__half*)alloc((size_t)n * DIM * 2);       // layer-2 agg out
    unsigned int*  bufT0   = (unsigned int*)alloc((size_t)n * DIM);     // T' ping
    unsigned int*  bufT1   = (unsigned int*)alloc((size_t)n * DIM);     // T' pong
    float*         dis     = (float*)alloc((size_t)n * 4);
    int2*          rowse   = (int2*)alloc((size_t)n * 8);               // {start,end} into ew
    int*           bincur  = (int*)alloc((size_t)NBIN * 16 * 4);
    unsigned int*  tmp     = (unsigned int*)alloc((size_t)NBIN * PAD * 4); // packed {src,dstlo}
    int*           ew      = (int*)alloc((size_t)NBIN * PAD * 4);       // padded CSR cols
    _Float16*      bp      = (_Float16*)alloc((size_t)3 * 2048 * 8 * 2);
    (void)ws_size;

    const int binBlocks = (E + EPB - 1) / EPB;      // 196

    prep_k<<<24, 256, 0, stream>>>(conv_w, bp, bincur, NBIN * 16);
    bin_k<<<binBlocks, 1024, 0, stream>>>(src, dst, bincur, tmp, E, NBIN);
    fused_k<<<NBIN, 1024, 0, stream>>>(tmp, bincur, rowse, dis, ew, n);

    const int tileBlocks = (n + 63) / 64;     // 1563
    const int aggBlocks  = (n + 15) / 16;     // 6250

    // layer 0: x (fp32) -> T'0
    gemm_k<<<tileBlocks, 256, 0, stream>>>(x, bp + 0 * 16384, dis, bufT0, n);
    // agg0 + gemm1 -> T'1   (no HBM round-trip for O0)
    aggemm_k<<<tileBlocks, 256, 0, stream>>>(bufT0, rowse, ew, dis,
                                             conv_b + 0 * DIM, bp + 1 * 16384, bufT1, n);
    // agg1 + gemm2 -> T'2
    aggemm_k<<<tileBlocks, 256, 0, stream>>>(bufT1, rowse, ew, dis,
                                             conv_b + 1 * DIM, bp + 2 * 16384, bufT0, n);
    // agg2 -> bufH
    agg_k<<<aggBlocks, 256, 0, stream>>>(bufT0, rowse, ew, dis, conv_b + 2 * DIM, bufH, n);

    poolhead_k<<<n_graphs, 1024, 0, stream>>>(bufH, batch, lin1_w, lin1_b, lin2_w, lin2_b, out, n);
}

// Round 11
// 282.783 us; speedup vs baseline: 1.1124x; 1.1039x over previous
//
#include <hip/hip_runtime.h>
#include <hip/hip_fp16.h>
#include <math.h>

#define DIM 128
#define BINSH 10       // 1024 nodes per dst-bin
#define EPB 8192       // edges per bin_k block (196 blocks x 1024 thr)
#define PAD 18432      // padded bin capacity: mean 16384 + 16 sigma
#define ALH 136        // LDS row stride in halves (agg->gemm handoff)
// Build discipline (R6): per-EDGE global atomics ping-pong cache lines across
// the 8 non-coherent XCD L2s — catastrophic. All per-edge counting in LDS.
// R15: scatter RESERVATION RUNS must stay multi-line — concurrency via waves
// per block, not block count. R16 (verified): 1024-thr build blocks,
// padded-bin tmp. R18 (verified): T' = dis*(h@W) fold, weightless 4B ew.
// R19 (verified, 411->310): parallel pool geometry. R20 FAILED: cooperative
// launch silently no-ops under graph capture. R21 (neutral): gather
// bytes-per-request ladder exhausted; agg is at the memory-system ceiling.
// R22 (neutral, 312): agg->gemm LDS fusion with 64-node blocks CUT GRID TO
// 1563 blocks -> occupancy 68%->30% -> agg phase 1.6x slower, ate the
// fusion's savings. Lesson (same family as R19): fusion must preserve the
// GRID PARALLELISM of what it fuses, not just its inner geometry.
// R23: aggemm v2 — 16-node blocks (grid 6250, = agg_k). Phase A identical
// to R19 agg; 16 output rows -> 4.3KB LDS tile. Phase B: the gemm's 8
// independent c-chunks split 2-per-wave over the same 16 rows.

typedef __attribute__((ext_vector_type(8))) _Float16 half8;
typedef __attribute__((ext_vector_type(4))) float f32x4;
typedef __attribute__((ext_vector_type(2))) float f32x2;

// ---------------------------------------------------------------------------
// prep: zero bincur + weight pre-pack (conv_w fp32 -> fp16 MFMA fragments)
// ---------------------------------------------------------------------------
__global__ __launch_bounds__(256) void prep_k(const float* __restrict__ conv_w,
                                              _Float16* __restrict__ bp,
                                              int* __restrict__ bincur, int nbc) {
    int g = blockIdx.x * 256 + threadIdx.x;   // 24*256 = 6144 >= max(nbc, 3*2048)
    if (g < nbc) bincur[g] = 0;
    if (g >= 3 * 2048) return;
    int l = g >> 11;
    int rem = g & 2047;
    int c = rem >> 8;
    int f = (rem >> 6) & 3;
    int lane = rem & 63;
    const float* W = conv_w + l * DIM * DIM;
    int kbase = f * 32 + (lane >> 4) * 8;
    int col = c * 16 + (lane & 15);
    _Float16* d = bp + ((size_t)l * 2048 + (size_t)(c * 4 + f) * 64 + lane) * 8;
#pragma unroll
    for (int j = 0; j < 8; ++j)
        d[j] = (_Float16)W[(kbase + j) * DIM + col];
}

// ---------------------------------------------------------------------------
// Graph build: bin -> fused(hist+scan+rowse+dis+scatter)
// ---------------------------------------------------------------------------
__global__ __launch_bounds__(1024) void bin_k(const int* __restrict__ src,
                                              const int* __restrict__ dst,
                                              int* __restrict__ bincur,
                                              unsigned int* __restrict__ tmp,
                                              int E, int NBIN) {
    __shared__ int cur[128];
    const int t = threadIdx.x;
    if (t < 128) cur[t] = 0;
    __syncthreads();
    const int e0 = blockIdx.x * EPB;
    const int e1 = min(e0 + EPB, E);
    for (int e = e0 + t; e < e1; e += 1024)
        atomicAdd(&cur[dst[e] >> BINSH], 1);
    __syncthreads();
    if (t < NBIN) {
        int h = cur[t];
        cur[t] = h ? atomicAdd(&bincur[t * 16], h) : 0;
    }
    __syncthreads();
    for (int e = e0 + t; e < e1; e += 1024) {
        int d = dst[e], s = src[e];
        int b = d >> BINSH;
        int pos = atomicAdd(&cur[b], 1);
        if (pos < PAD)
            tmp[(size_t)b * PAD + pos] =
                (unsigned int)((s << BINSH) | (d & ((1 << BINSH) - 1)));
    }
}

// One block per bin. Stage bin in LDS, histogram, scan, emit rowse/dis,
// scatter cols to padded ew (start = b*PAD + excl). No cross-bin dependency.
__global__ __launch_bounds__(1024) void fused_k(const unsigned int* __restrict__ tmp,
                                                const int* __restrict__ bincur,
                                                int2* __restrict__ rowse,
                                                float* __restrict__ dis,
                                                int* __restrict__ ew, int n) {
    __shared__ unsigned int led[PAD];
    __shared__ int cnt[1 << BINSH];
    __shared__ int lcur[1 << BINSH];
    const int b = blockIdx.x, t = threadIdx.x;
    const int size = min(bincur[b * 16], PAD);
    const unsigned int* bt = tmp + (size_t)b * PAD;
    cnt[t] = 0;
    for (int e = t; e < size; e += 1024) led[e] = bt[e];
    __syncthreads();
    for (int e = t; e < size; e += 1024)
        atomicAdd(&cnt[led[e] & ((1 << BINSH) - 1)], 1);
    __syncthreads();
    int v = cnt[t];
    __syncthreads();
    for (int off = 1; off < 1024; off <<= 1) {      // inclusive ripple scan
        int u = (t >= off) ? cnt[t - off] : 0;
        __syncthreads();
        cnt[t] += u;
        __syncthreads();
    }
    int start = b * PAD + cnt[t] - v;
    lcur[t] = start;
    int node = (b << BINSH) + t;
    if (node < n) {
        rowse[node] = make_int2(start, start + v);
        dis[node] = rsqrtf((float)(v + 1));
    }
    __syncthreads();
    for (int e = t; e < size; e += 1024) {
        unsigned int u = led[e];
        int q = atomicAdd(&lcur[u & ((1 << BINSH) - 1)], 1);
        ew[q] = (int)(u >> BINSH);
    }
}

// ---------------------------------------------------------------------------
// Shared agg inner loop (R19 uint2 geometry): accumulate sum of T' rows
// listed in ew[e0..e1) at word-pair li into acc[8]. Weightless (T' fold).
// ---------------------------------------------------------------------------
#define ACC_EDGE(rr) { \
    f32x2 a0 = __builtin_amdgcn_cvt_pk_f32_fp8((int)rr.x, 0); \
    f32x2 a1 = __builtin_amdgcn_cvt_pk_f32_fp8((int)rr.x, 1); \
    f32x2 a2 = __builtin_amdgcn_cvt_pk_f32_fp8((int)rr.y, 0); \
    f32x2 a3 = __builtin_amdgcn_cvt_pk_f32_fp8((int)rr.y, 1); \
    acc[0] += a0[0]; acc[1] += a0[1]; \
    acc[2] += a1[0]; acc[3] += a1[1]; \
    acc[4] += a2[0]; acc[5] += a2[1]; \
    acc[6] += a3[0]; acc[7] += a3[1]; }

__device__ __forceinline__ void agg_edges(const uint2* __restrict__ T2,
                                          const int* __restrict__ ew,
                                          int e0, int e1, int li, float* acc) {
    int e = e0;
    for (; e + 8 <= e1; e += 8) {
        int c0 = ew[e + 0], c1 = ew[e + 1], c2 = ew[e + 2], c3 = ew[e + 3];
        int c4 = ew[e + 4], c5 = ew[e + 5], c6 = ew[e + 6], c7 = ew[e + 7];
        uint2 r0 = T2[(size_t)c0 * 16 + li];
        uint2 r1 = T2[(size_t)c1 * 16 + li];
        uint2 r2 = T2[(size_t)c2 * 16 + li];
        uint2 r3 = T2[(size_t)c3 * 16 + li];
        uint2 r4 = T2[(size_t)c4 * 16 + li];
        uint2 r5 = T2[(size_t)c5 * 16 + li];
        uint2 r6 = T2[(size_t)c6 * 16 + li];
        uint2 r7 = T2[(size_t)c7 * 16 + li];
        ACC_EDGE(r0); ACC_EDGE(r1); ACC_EDGE(r2); ACC_EDGE(r3);
        ACC_EDGE(r4); ACC_EDGE(r5); ACC_EDGE(r6); ACC_EDGE(r7);
    }
    for (; e + 4 <= e1; e += 4) {
        int c0 = ew[e + 0], c1 = ew[e + 1], c2 = ew[e + 2], c3 = ew[e + 3];
        uint2 r0 = T2[(size_t)c0 * 16 + li];
        uint2 r1 = T2[(size_t)c1 * 16 + li];
        uint2 r2 = T2[(size_t)c2 * 16 + li];
        uint2 r3 = T2[(size_t)c3 * 16 + li];
        ACC_EDGE(r0); ACC_EDGE(r1); ACC_EDGE(r2); ACC_EDGE(r3);
    }
    for (; e + 2 <= e1; e += 2) {
        int c0 = ew[e + 0], c1 = ew[e + 1];
        uint2 r0 = T2[(size_t)c0 * 16 + li];
        uint2 r1 = T2[(size_t)c1 * 16 + li];
        ACC_EDGE(r0); ACC_EDGE(r1);
    }
    if (e < e1) {
        uint2 r0 = T2[(size_t)ew[e] * 16 + li];
        ACC_EDGE(r0);
    }
}

// ---------------------------------------------------------------------------
// MFMA GEMM (layer 0 only): T'[n,128](fp8) = dis * (x @ W0), fp32 input,
// direct global->reg A-fragments (R17).
// ---------------------------------------------------------------------------
__global__ __launch_bounds__(256) void gemm_k(const float* __restrict__ Ain,
                                              const _Float16* __restrict__ Bp,
                                              const float* __restrict__ dis,
                                              unsigned int* __restrict__ T32, int n) {
    const int t = threadIdx.x;
    const int lane = t & 63;
    const int wave = t >> 6;
    const int quad = lane >> 4;
    const int m    = lane & 15;
    const int row  = blockIdx.x * 64 + wave * 16 + m;
    const bool act = row < n;

    half8 a[4];
    float dvr = 0.f;
    if (act) {
        dvr = dis[row];
        const float* A = Ain + (size_t)row * DIM;
#pragma unroll
        for (int f = 0; f < 4; ++f) {
            float4 v0 = *(const float4*)(A + f * 32 + quad * 8);
            float4 v1 = *(const float4*)(A + f * 32 + quad * 8 + 4);
            __half2 h01 = __floats2half2_rn(v0.x, v0.y);
            __half2 h23 = __floats2half2_rn(v0.z, v0.w);
            __half2 h45 = __floats2half2_rn(v1.x, v1.y);
            __half2 h67 = __floats2half2_rn(v1.z, v1.w);
            int4 pk;
            pk.x = *(int*)&h01; pk.y = *(int*)&h23;
            pk.z = *(int*)&h45; pk.w = *(int*)&h67;
            a[f] = *(half8*)&pk;
        }
    } else {
#pragma unroll
        for (int f = 0; f < 4; ++f) a[f] = half8{};
    }

    const half8* B8 = (const half8*)Bp;   // 32KB/layer, hot in L1/L2
#pragma unroll
    for (int c = 0; c < 8; ++c) {
        f32x4 acc = {0.f, 0.f, 0.f, 0.f};
#pragma unroll
        for (int f = 0; f < 4; ++f) {
            half8 b = B8[(c * 4 + f) * 64 + lane];
            acc = __builtin_amdgcn_mfma_f32_16x16x32_f16(b, a[f], acc, 0, 0, 0);
        }
        if (act) {
            int r = 0;
            r = __builtin_amdgcn_cvt_pk_fp8_f32(dvr * acc[0], dvr * acc[1], r, 0);
            r = __builtin_amdgcn_cvt_pk_fp8_f32(dvr * acc[2], dvr * acc[3], r, 1);
            T32[(size_t)row * 32 + c * 4 + quad] = (unsigned int)r;
        }
    }
}

// ---------------------------------------------------------------------------
// R23 fused agg_l + gemm_{l+1}, 16-node blocks (grid = (n+15)/16 = agg_k's):
// Phase A: R19 agg geometry verbatim (4 waves x 4 nodes, lane li owns 8
// dims); O rows -> 4.3KB LDS tile. One __syncthreads.
// Phase B: all 4 waves read the same 16 rows' a[4] fragments from LDS; the
// 8 independent c-chunks split 2 per wave (8 MFMA/wave).
// ---------------------------------------------------------------------------
__global__ __launch_bounds__(256) void aggemm_k(const unsigned int* __restrict__ Tin,
                                                const int2* __restrict__ rowse,
                                                const int* __restrict__ ew,
                                                const float* __restrict__ dis,
                                                const float* __restrict__ bias,
                                                const _Float16* __restrict__ Bp,
                                                unsigned int* __restrict__ Tout,
                                                int n) {
    __shared__ _Float16 Al[16 * ALH];
    const int lane = threadIdx.x & 63;
    const int wv   = threadIdx.x >> 6;   // wave 0..3
    const int li   = lane & 15;          // word-pair (8 dims) within row
    const int qd   = lane >> 4;          // node within wave's quartet
    const int r0   = blockIdx.x * 16;
    const uint2* T2 = (const uint2*)Tin;

    // ---- Phase A: aggregate 16 rows into LDS (R19 geometry) ----
    {
        const int lrow = wv * 4 + qd;
        const int v = r0 + lrow;
        const bool act = v < n;
        int e0 = 0, e1 = 0;
        float dv = 0.f;
        if (act) {
            int2 re = rowse[v];
            e0 = re.x; e1 = re.y;
            dv = dis[v];
        }
        float acc[8] = {0.f, 0.f, 0.f, 0.f, 0.f, 0.f, 0.f, 0.f};
        if (act) {
            uint2 rs = T2[(size_t)v * 16 + li];
            ACC_EDGE(rs);
        }
        agg_edges(T2, ew, e0, e1, li, acc);

        float4 b0 = ((const float4*)bias)[li * 2 + 0];
        float4 b1 = ((const float4*)bias)[li * 2 + 1];
        int4 o = make_int4(0, 0, 0, 0);
        if (act) {
            __half2 o0 = __floats2half2_rn(fmaxf(dv * acc[0] + b0.x, 0.f),
                                           fmaxf(dv * acc[1] + b0.y, 0.f));
            __half2 o1 = __floats2half2_rn(fmaxf(dv * acc[2] + b0.z, 0.f),
                                           fmaxf(dv * acc[3] + b0.w, 0.f));
            __half2 o2 = __floats2half2_rn(fmaxf(dv * acc[4] + b1.x, 0.f),
                                           fmaxf(dv * acc[5] + b1.y, 0.f));
            __half2 o3 = __floats2half2_rn(fmaxf(dv * acc[6] + b1.z, 0.f),
                                           fmaxf(dv * acc[7] + b1.w, 0.f));
            o.x = *(int*)&o0; o.y = *(int*)&o1; o.z = *(int*)&o2; o.w = *(int*)&o3;
        }
        *(int4*)&Al[lrow * ALH + li * 8] = o;
    }
    __syncthreads();

    // ---- Phase B: gemm from LDS; c-chunks 2wv, 2wv+1 over the same 16 rows ----
    const int quad = lane >> 4;
    const int m    = lane & 15;
    const int row  = r0 + m;
    const bool act = row < n;

    half8 a[4];
#pragma unroll
    for (int f = 0; f < 4; ++f)
        a[f] = *(const half8*)&Al[m * ALH + f * 32 + quad * 8];
    float dvr = act ? dis[row] : 0.f;

    const half8* B8 = (const half8*)Bp;
#pragma unroll
    for (int cc = 0; cc < 2; ++cc) {
        const int c = wv * 2 + cc;
        f32x4 acc = {0.f, 0.f, 0.f, 0.f};
#pragma unroll
        for (int f = 0; f < 4; ++f) {
            half8 b = B8[(c * 4 + f) * 64 + lane];
            acc = __builtin_amdgcn_mfma_f32_16x16x32_f16(b, a[f], acc, 0, 0, 0);
        }
        if (act) {
            int r = 0;
            r = __builtin_amdgcn_cvt_pk_fp8_f32(dvr * acc[0], dvr * acc[1], r, 0);
            r = __builtin_amdgcn_cvt_pk_fp8_f32(dvr * acc[2], dvr * acc[3], r, 1);
            Tout[(size_t)row * 32 + c * 4 + quad] = (unsigned int)r;
        }
    }
}

// ---------------------------------------------------------------------------
// Final aggregation (layer 2, R19 uint2 geometry): O -> bufH fp16 for pool.
// ---------------------------------------------------------------------------
__global__ __launch_bounds__(256) void agg_k(const unsigned int* __restrict__ T32,
                                             const int2* __restrict__ rowse,
                                             const int* __restrict__ ew,
                                             const float* __restrict__ dis,
                                             const float* __restrict__ bias,
                                             __half* __restrict__ O, int n) {
    const int lane = threadIdx.x & 63;
    const int li   = lane & 15;
    const int v = blockIdx.x * 16 + (threadIdx.x >> 6) * 4 + (lane >> 4);
    const bool act = v < n;

    const uint2* T2 = (const uint2*)T32;

    int e0 = 0, e1 = 0;
    float dv = 0.f;
    if (act) {
        int2 re = rowse[v];
        e0 = re.x; e1 = re.y;
        dv = dis[v];
    }

    float acc[8] = {0.f, 0.f, 0.f, 0.f, 0.f, 0.f, 0.f, 0.f};
    if (act) {
        uint2 rs = T2[(size_t)v * 16 + li];
        ACC_EDGE(rs);
    }
    agg_edges(T2, ew, e0, e1, li, acc);

    if (act) {
        float4 b0 = ((const float4*)bias)[li * 2 + 0];
        float4 b1 = ((const float4*)bias)[li * 2 + 1];
        __half2 o0 = __floats2half2_rn(fmaxf(dv * acc[0] + b0.x, 0.f),
                                       fmaxf(dv * acc[1] + b0.y, 0.f));
        __half2 o1 = __floats2half2_rn(fmaxf(dv * acc[2] + b0.z, 0.f),
                                       fmaxf(dv * acc[3] + b0.w, 0.f));
        __half2 o2 = __floats2half2_rn(fmaxf(dv * acc[4] + b1.x, 0.f),
                                       fmaxf(dv * acc[5] + b1.y, 0.f));
        __half2 o3 = __floats2half2_rn(fmaxf(dv * acc[6] + b1.z, 0.f),
                                       fmaxf(dv * acc[7] + b1.w, 0.f));
        int4 o;
        o.x = *(int*)&o0; o.y = *(int*)&o1; o.z = *(int*)&o2; o.w = *(int*)&o3;
        *(int4*)(O + (size_t)v * DIM + li * 8) = o;
    }
}

// ---------------------------------------------------------------------------
// Fused pool+head (R19 parallel geometry): 1024 threads = 64 row-groups x 16
// lanes; LDS tree-reduce; head on threads 0-127.
// ---------------------------------------------------------------------------
__global__ __launch_bounds__(1024) void poolhead_k(const __half* __restrict__ H,
                                                   const int* __restrict__ batch,
                                                   const float* __restrict__ l1w,
                                                   const float* __restrict__ l1b,
                                                   const float* __restrict__ l2w,
                                                   const float* __restrict__ l2b,
                                                   float* __restrict__ out, int n) {
    const int g = blockIdx.x, t = threadIdx.x;
    const int g8 = t >> 4;          // row-group 0..63
    const int li = t & 15;          // int4 (8 dims) within row
    __shared__ float red[1024 * 8];  // 32 KB partials
    __shared__ float gs[128];

    int lo = 0, hi = n;
    while (lo < hi) { int m = (lo + hi) >> 1; if (batch[m] < g) lo = m + 1; else hi = m; }
    int start = lo;
    lo = start; hi = n;
    while (lo < hi) { int m = (lo + hi) >> 1; if (batch[m] < g + 1) lo = m + 1; else hi = m; }
    int end = lo;
    int cnt = end - start;

    float s[8] = {0.f, 0.f, 0.f, 0.f, 0.f, 0.f, 0.f, 0.f};
    for (int v = start + g8; v < end; v += 64) {
        int4 pk = *((const int4*)(H + (size_t)v * DIM) + li);
        const __half2* h2 = (const __half2*)&pk;
#pragma unroll
        for (int j = 0; j < 4; ++j) {
            float2 f = __half22float2(h2[j]);
            s[2 * j + 0] += f.x;
            s[2 * j + 1] += f.y;
        }
    }
#pragma unroll
    for (int j = 0; j < 8; ++j) red[t * 8 + j] = s[j];
    __syncthreads();
    for (int st = 32; st > 0; st >>= 1) {
        if (g8 < st) {
#pragma unroll
            for (int j = 0; j < 8; ++j)
                red[t * 8 + j] += red[(t + st * 16) * 8 + j];
        }
        __syncthreads();
    }
    if (t < 16) {
        float inv = cnt > 0 ? 1.f / (float)cnt : 0.f;
#pragma unroll
        for (int j = 0; j < 8; ++j) gs[t * 8 + j] = red[t * 8 + j] * inv;
    }
    __syncthreads();

    // head on threads 0..127
    float y = 0.f;
    if (t < 128) {
        float acc = l1b[t];
        for (int k = 0; k < 128; ++k) acc += gs[k] * l1w[k * 128 + t];
        y = fmaxf(acc, 0.f);
    }
    float2* red2 = (float2*)red;
    if (t < 128) red2[t] = make_float2(y * l2w[t * 2 + 0], y * l2w[t * 2 + 1]);
    __syncthreads();
    for (int sfd = 64; sfd > 0; sfd >>= 1) {
        if (t < sfd) {
            red2[t].x += red2[t + sfd].x;
            red2[t].y += red2[t + sfd].y;
        }
        __syncthreads();
    }
    if (t == 0) {
        float l0 = red2[0].x + l2b[0];
        float l1 = red2[0].y + l2b[1];
        float m = fmaxf(l0, l1);
        float lse = m + logf(expf(l0 - m) + expf(l1 - m));
        out[g * 2 + 0] = l0 - lse;
        out[g * 2 + 1] = l1 - lse;
    }
}

// ---------------------------------------------------------------------------
// Launch — 8 graph nodes: prep, bin, fused, gemm0, AG1, AG2, agg2, poolhead
// ---------------------------------------------------------------------------
extern "C" void kernel_launch(void* const* d_in, const int* in_sizes, int n_in,
                              void* d_out, int out_size, void* d_ws, size_t ws_size,
                              hipStream_t stream) {
    const float* x       = (const float*)d_in[0];
    const int*   ei      = (const int*)d_in[1];
    const int*   batch   = (const int*)d_in[2];
    const float* conv_w  = (const float*)d_in[3];
    const float* conv_b  = (const float*)d_in[4];
    const float* lin1_w  = (const float*)d_in[5];
    const float* lin1_b  = (const float*)d_in[6];
    const float* lin2_w  = (const float*)d_in[7];
    const float* lin2_b  = (const float*)d_in[8];
    float* out = (float*)d_out;

    const int n = in_sizes[0] / DIM;      // 100000
    const int E = in_sizes[1] / 2;        // 1600000
    const int n_graphs = 128;
    const int NBIN = (n + (1 << BINSH) - 1) >> BINSH;   // 98 dst-bins

    const int* src = ei;
    const int* dst = ei + E;

    // workspace layout (all 256B aligned)
    char* p = (char*)d_ws;
    auto alloc = [&](size_t bytes) {
        char* r = p;
        p += (bytes + 255) & ~(size_t)255;
        return r;
    };
    __half*        bufH    = (__half*)alloc((size_t)n * DIM * 2);       // layer-2 agg out
    unsigned int*  bufT0   = (unsigned int*)alloc((size_t)n * DIM);     // T' ping
    unsigned int*  bufT1   = (unsigned int*)alloc((size_t)n * DIM);     // T' pong
    float*         dis     = (float*)alloc((size_t)n * 4);
    int2*          rowse   = (int2*)alloc((size_t)n * 8);               // {start,end} into ew
    int*           bincur  = (int*)alloc((size_t)NBIN * 16 * 4);
    unsigned int*  tmp     = (unsigned int*)alloc((size_t)NBIN * PAD * 4); // packed {src,dstlo}
    int*           ew      = (int*)alloc((size_t)NBIN * PAD * 4);       // padded CSR cols
    _Float16*      bp      = (_Float16*)alloc((size_t)3 * 2048 * 8 * 2);
    (void)ws_size;

    const int binBlocks = (E + EPB - 1) / EPB;      // 196

    prep_k<<<24, 256, 0, stream>>>(conv_w, bp, bincur, NBIN * 16);
    bin_k<<<binBlocks, 1024, 0, stream>>>(src, dst, bincur, tmp, E, NBIN);
    fused_k<<<NBIN, 1024, 0, stream>>>(tmp, bincur, rowse, dis, ew, n);

    const int gemmBlocks = (n + 63) / 64;     // 1563
    const int aggBlocks  = (n + 15) / 16;     // 6250

    // layer 0: x (fp32) -> T'0
    gemm_k<<<gemmBlocks, 256, 0, stream>>>(x, bp + 0 * 16384, dis, bufT0, n);
    // agg0 + gemm1 -> T'1   (no HBM round-trip for O0)
    aggemm_k<<<aggBlocks, 256, 0, stream>>>(bufT0, rowse, ew, dis,
                                            conv_b + 0 * DIM, bp + 1 * 16384, bufT1, n);
    // agg1 + gemm2 -> T'2
    aggemm_k<<<aggBlocks, 256, 0, stream>>>(bufT1, rowse, ew, dis,
                                            conv_b + 1 * DIM, bp + 2 * 16384, bufT0, n);
    // agg2 -> bufH
    agg_k<<<aggBlocks, 256, 0, stream>>>(bufT0, rowse, ew, dis, conv_b + 2 * DIM, bufH, n);

    poolhead_k<<<n_graphs, 1024, 0, stream>>>(bufH, batch, lin1_w, lin1_b, lin2_w, lin2_b, out, n);
}